// Round 5
// baseline (180.250 us; speedup 1.0000x reference)
//
#include <hip/hip_runtime.h>

// Predictor_8924942041234 — 2-hop rule grounding over a KG, ONE dispatch.
// x0 one-hot -> hop1 frontier (~640 matching edges); rules collapse to
// W[r1][r2] (24x24); hop2 = stream all E edges + O(1) per-head-entity chain
// probe. Dispatch fixed cost (~8 us each) dominates over device time (~5 us),
// so all phases are fused into one plain launch with a software grid barrier
// (round-3 hipLaunchCooperativeKernel silently failed to launch).
//
// Barrier safety: grid = 512 blocks = 2 blocks/CU x 256 CUs, guaranteed
// co-resident by __launch_bounds__(256,2) (VGPR<=128, LDS 2.8KB) -> no
// deadlock; bounded spin as a belt-and-braces guard. Barrier words live in
// poisoned ws (0xAA): block 0 stores count=0 then release-stores MAGIC
// (!= poison, != 0); arrivers acquire-spin on MAGIC before adding.
// headptr needs no init: entries store e+1 (>=1); poison/zero reads <= 0.

namespace {
constexpr int kNEnt    = 20000;
constexpr int kNRel    = 24;
constexpr int kNEdge   = 200000;
constexpr int kBatch   = 64;
constexpr int kNRules  = 32;
constexpr int kWSz     = kNRel * kNRel;          // 576
constexpr int kBlocks  = 512;                    // 2 blocks/CU -> co-resident
constexpr int kT       = 256;
constexpr int kGT      = kBlocks * kT;           // 131072
constexpr int kScore4  = kBatch * kNEnt / 4;     // 320000 float4 (score)
constexpr int kOut4    = 2 * kScore4;            // 640000 float4 (score+mask)
constexpr unsigned kMagic     = 0x5EEDF00Du;
constexpr unsigned kSpinLimit = 1u << 22;        // hang guard, never hit
// ws layout (bytes):
//   0       headptr[20000] int   (e+1 of chain head; <=0 empty; NO init)
//   81920   barA (arrival count)   — own cache line
//   82048   barB (init-magic flag) — own cache line
//   90112   nodeNext[200000] u32 (prev headptr value (or 0) | r1<<24)
//   983040  nodeBm[200000] u64   (which b's matched hop1 edge e)
}

__global__ void __launch_bounds__(kT, 2) k_fused(
        const int* __restrict__ all_h,
        const int* __restrict__ rem,
        const int* __restrict__ eh,
        const int* __restrict__ er,
        const int* __restrict__ et,
        const int* __restrict__ rb,
        const float* __restrict__ rw,
        const float* __restrict__ bias,
        float* __restrict__ out,
        int* __restrict__ headptr,
        unsigned* __restrict__ nodeNext,
        unsigned long long* __restrict__ nodeBm,
        unsigned* __restrict__ barA,
        unsigned* __restrict__ barB) {
    __shared__ int   sh[kBatch];
    __shared__ int   srem[kBatch];
    __shared__ float sW[kWSz];
    const int t = threadIdx.x;

    // barrier init handshake (block 0 is guaranteed resident)
    if (blockIdx.x == 0 && t == 0) {
        __hip_atomic_store(barA, 0u, __ATOMIC_RELAXED, __HIP_MEMORY_SCOPE_AGENT);
        __hip_atomic_store(barB, kMagic, __ATOMIC_RELEASE, __HIP_MEMORY_SCOPE_AGENT);
    }

    if (t < kBatch) sh[t] = all_h[t];
    else if (t < 2 * kBatch) srem[t - kBatch] = rem[t - kBatch];
    for (int i = t; i < kWSz; i += kT) sW[i] = 0.f;
    __syncthreads();
    if (t < kNRules)
        atomicAdd(&sW[rb[2 * t] * kNRel + rb[2 * t + 1]], rw[t]);
    // (sW is only read in phase C, after the post-barrier __syncthreads)

    const int gid = blockIdx.x * kT + t;

    // ---- Phase A: out init — score[b,:]=bias, mask[b,:]=1 ----
    for (int i = gid; i < kOut4; i += kGT) {
        if (i < kScore4)
            ((float4*)out)[i] = ((const float4*)bias)[i % (kNEnt / 4)];
        else
            ((float4*)out)[i] = make_float4(1.f, 1.f, 1.f, 1.f);
    }

    // ---- Phase B: hop1 frontier -> per-tail-entity chains ----
    for (int e = gid; e < kNEdge; e += kGT) {
        int h = eh[e];
        unsigned long long bm = 0ull;
        for (int b = 0; b < kBatch; b++)
            bm |= (unsigned long long)(sh[b] == h) << b;
        if (!bm) continue;
        bool removed = false;
        for (int i = 0; i < kBatch; i++) removed |= (srem[i] == e);
        if (removed) continue;
        int old = atomicExch(&headptr[et[e]], e + 1);       // store e+1 (>=1)
        nodeNext[e] = ((old <= 0) ? 0u : (unsigned)old)     // poison/0 -> end
                    | ((unsigned)er[e] << 24);
        nodeBm[e]   = bm;
    }

    // ---- software grid barrier (release writes, acquire reads) ----
    __threadfence();
    __syncthreads();
    if (t == 0) {
        unsigned tries = 0;
        while (__hip_atomic_load(barB, __ATOMIC_ACQUIRE,
                                 __HIP_MEMORY_SCOPE_AGENT) != kMagic &&
               ++tries < kSpinLimit)
            __builtin_amdgcn_s_sleep(4);
        __hip_atomic_fetch_add(barA, 1u, __ATOMIC_ACQ_REL,
                               __HIP_MEMORY_SCOPE_AGENT);
        tries = 0;
        while (__hip_atomic_load(barA, __ATOMIC_ACQUIRE,
                                 __HIP_MEMORY_SCOPE_AGENT) < (unsigned)kBlocks &&
               ++tries < kSpinLimit)
            __builtin_amdgcn_s_sleep(4);
    }
    __syncthreads();
    __threadfence();

    // ---- Phase C: hop2 — stream edges, probe chain, scatter W ----
    for (int e = gid; e < kNEdge; e += kGT) {
        int h = eh[e];
        int p = headptr[h];
        if (p <= 0) continue;                      // ~97% of edges exit here
        bool removed = false;
        for (int i = 0; i < kBatch; i++) removed |= (srem[i] == e);
        if (removed) continue;
        int r2 = er[e];
        int t2 = et[e];
        while (p > 0) {
            int e1 = p - 1;
            unsigned nx           = nodeNext[e1];
            unsigned long long bm = nodeBm[e1];
            float w = sW[((nx >> 24) & 31u) * kNRel + r2];
            while (bm) {
                int b = __ffsll(bm) - 1;
                bm &= bm - 1;
                atomicAdd(&out[b * kNEnt + t2], w);
            }
            p = (int)(nx & 0xFFFFFFu);
        }
    }
}

extern "C" void kernel_launch(void* const* d_in, const int* in_sizes, int n_in,
                              void* d_out, int out_size, void* d_ws, size_t ws_size,
                              hipStream_t stream) {
    const int*   all_h = (const int*)d_in[0];
    // d_in[1] = all_r (unused by the reference)
    const int*   rem   = (const int*)d_in[2];
    const int*   eh    = (const int*)d_in[3];
    const int*   er    = (const int*)d_in[4];
    const int*   et    = (const int*)d_in[5];
    const int*   rb    = (const int*)d_in[6];
    const float* rw    = (const float*)d_in[7];
    const float* bias  = (const float*)d_in[8];
    float* out = (float*)d_out;

    char* ws = (char*)d_ws;
    int*                headptr  = (int*)(ws + 0);
    unsigned*           barA     = (unsigned*)(ws + 81920);
    unsigned*           barB     = (unsigned*)(ws + 82048);
    unsigned*           nodeNext = (unsigned*)(ws + 90112);
    unsigned long long* nodeBm   = (unsigned long long*)(ws + 983040);

    hipLaunchKernelGGL(k_fused, dim3(kBlocks), dim3(kT), 0, stream,
                       all_h, rem, eh, er, et, rb, rw, bias, out,
                       headptr, nodeNext, nodeBm, barA, barB);
}

// Round 6
// 122.872 us; speedup vs baseline: 1.4670x; 1.4670x over previous
//
#include <hip/hip_runtime.h>

// Predictor_8924942041234 — 2-hop rule grounding over a KG, ONE dispatch.
// x0 one-hot -> hop1 frontier (~640 matching edges); rules collapse to
// W[r1][r2] (24x24); hop2 = stream all E edges + O(1) per-head-entity chain
// probe. One plain launch with a software grid barrier.
//
// ROUND-5 LESSON: agent-scope ACQUIRE inside a spin loop emits buffer_inv
// (full L2 invalidate) EVERY iteration -> 115 us coherence storm. Fix: spin
// with RELAXED atomics; heavyweight fences (__threadfence = wbl2/inv) exactly
// once per block, on thread 0 only, bracketed by __syncthreads().
//
// Barrier safety: 512 blocks = 2/CU x 256 CUs, co-resident via
// __launch_bounds__(256,2) (VGPR<=128, LDS 2.8KB) -> no deadlock; bounded
// spin as a guard. Barrier words live in poisoned ws (0xAA): block 0 stores
// count=0 then release-stores MAGIC; arrivers spin (relaxed) on MAGIC first.
// headptr needs no init: entries store e+1 (>=1); poison/zero reads <= 0.
// Phase-C edge data (h,r2,t2,removed) is preloaded into registers during the
// phase-B pass (same indices) so the post-barrier L2 invalidate costs no
// edge-array refetch.

namespace {
constexpr int kNEnt    = 20000;
constexpr int kNRel    = 24;
constexpr int kNEdge   = 200000;
constexpr int kBatch   = 64;
constexpr int kNRules  = 32;
constexpr int kWSz     = kNRel * kNRel;          // 576
constexpr int kBlocks  = 512;                    // 2 blocks/CU -> co-resident
constexpr int kT       = 256;
constexpr int kGT      = kBlocks * kT;           // 131072
constexpr int kScore4  = kBatch * kNEnt / 4;     // 320000 float4 (score)
constexpr int kOut4    = 2 * kScore4;            // 640000 float4 (score+mask)
constexpr unsigned kMagic     = 0x5EEDF00Du;
constexpr unsigned kSpinLimit = 1u << 22;        // hang guard, never hit
// ws layout (bytes):
//   0       headptr[20000] int   (e+1 of chain head; <=0 empty; NO init)
//   81920   barA (arrival count)   — own cache line
//   82048   barB (init-magic flag) — own cache line
//   90112   nodeNext[200000] u32 (prev headptr value (or 0) | r1<<24)
//   983040  nodeBm[200000] u64   (which b's matched hop1 edge e)
}

__global__ void __launch_bounds__(kT, 2) k_fused(
        const int* __restrict__ all_h,
        const int* __restrict__ rem,
        const int* __restrict__ eh,
        const int* __restrict__ er,
        const int* __restrict__ et,
        const int* __restrict__ rb,
        const float* __restrict__ rw,
        const float* __restrict__ bias,
        float* __restrict__ out,
        int* __restrict__ headptr,
        unsigned* __restrict__ nodeNext,
        unsigned long long* __restrict__ nodeBm,
        unsigned* __restrict__ barA,
        unsigned* __restrict__ barB) {
    __shared__ int   sh[kBatch];
    __shared__ int   srem[kBatch];
    __shared__ float sW[kWSz];
    const int t = threadIdx.x;

    // barrier init handshake (agent-scope atomics execute at the coherence
    // point — no stale-L2 hazard; release store orders barA=0 before MAGIC)
    if (blockIdx.x == 0 && t == 0) {
        __hip_atomic_store(barA, 0u, __ATOMIC_RELAXED, __HIP_MEMORY_SCOPE_AGENT);
        __hip_atomic_store(barB, kMagic, __ATOMIC_RELEASE, __HIP_MEMORY_SCOPE_AGENT);
    }

    if (t < kBatch) sh[t] = all_h[t];
    else if (t < 2 * kBatch) srem[t - kBatch] = rem[t - kBatch];
    for (int i = t; i < kWSz; i += kT) sW[i] = 0.f;
    __syncthreads();
    if (t < kNRules)
        atomicAdd(&sW[rb[2 * t] * kNRel + rb[2 * t + 1]], rw[t]);
    // (sW only read in phase C, after the post-barrier __syncthreads)

    const int gid = blockIdx.x * kT + t;

    // ---- Phase A: out init — score[b,:]=bias, mask[b,:]=1 ----
    for (int i = gid; i < kOut4; i += kGT) {
        if (i < kScore4)
            ((float4*)out)[i] = ((const float4*)bias)[i % (kNEnt / 4)];
        else
            ((float4*)out)[i] = make_float4(1.f, 1.f, 1.f, 1.f);
    }

    // ---- Phase B: hop1 frontier chains + register-preload for phase C ----
    int  ph[2], pr[2], pt[2];
    bool pok[2];
#pragma unroll
    for (int j = 0; j < 2; j++) {
        int e = gid + j * kGT;
        pok[j] = false;
        ph[j] = 0; pr[j] = 0; pt[j] = 0;
        if (e < kNEdge) {
            int h  = eh[e];
            int r  = er[e];
            int tl = et[e];
            bool removed = false;
            for (int i = 0; i < kBatch; i++) removed |= (srem[i] == e);
            if (!removed) {
                pok[j] = true; ph[j] = h; pr[j] = r; pt[j] = tl;
                unsigned long long bm = 0ull;
                for (int b = 0; b < kBatch; b++)
                    bm |= (unsigned long long)(sh[b] == h) << b;
                if (bm) {
                    int old = atomicExch(&headptr[tl], e + 1);  // e+1 >= 1
                    nodeNext[e] = ((old <= 0) ? 0u : (unsigned)old)
                                | ((unsigned)r << 24);
                    nodeBm[e]   = bm;
                }
            }
        }
    }

    // ---- software grid barrier: relaxed spins, fences once per block ----
    __syncthreads();
    if (t == 0) {
        __threadfence();                       // release: wbl2 once per block
        unsigned tries = 0;
        while (__hip_atomic_load(barB, __ATOMIC_RELAXED,
                                 __HIP_MEMORY_SCOPE_AGENT) != kMagic &&
               ++tries < kSpinLimit)
            __builtin_amdgcn_s_sleep(2);
        __hip_atomic_fetch_add(barA, 1u, __ATOMIC_RELAXED,
                               __HIP_MEMORY_SCOPE_AGENT);
        tries = 0;
        while (__hip_atomic_load(barA, __ATOMIC_RELAXED,
                                 __HIP_MEMORY_SCOPE_AGENT) < (unsigned)kBlocks &&
               ++tries < kSpinLimit)
            __builtin_amdgcn_s_sleep(2);
        __threadfence();                       // acquire: inv once per block
    }
    __syncthreads();

    // ---- Phase C: hop2 — probe chain per preloaded edge, scatter W ----
#pragma unroll
    for (int j = 0; j < 2; j++) {
        if (!pok[j]) continue;
        int p = headptr[ph[j]];
        if (p <= 0) continue;                  // ~97% of edges exit here
        int r2 = pr[j];
        int t2 = pt[j];
        while (p > 0) {
            int e1 = p - 1;
            unsigned nx           = nodeNext[e1];
            unsigned long long bm = nodeBm[e1];
            float w = sW[((nx >> 24) & 31u) * kNRel + r2];
            while (bm) {
                int b = __ffsll(bm) - 1;
                bm &= bm - 1;
                atomicAdd(&out[b * kNEnt + t2], w);
            }
            p = (int)(nx & 0xFFFFFFu);
        }
    }
}

extern "C" void kernel_launch(void* const* d_in, const int* in_sizes, int n_in,
                              void* d_out, int out_size, void* d_ws, size_t ws_size,
                              hipStream_t stream) {
    const int*   all_h = (const int*)d_in[0];
    // d_in[1] = all_r (unused by the reference)
    const int*   rem   = (const int*)d_in[2];
    const int*   eh    = (const int*)d_in[3];
    const int*   er    = (const int*)d_in[4];
    const int*   et    = (const int*)d_in[5];
    const int*   rb    = (const int*)d_in[6];
    const float* rw    = (const float*)d_in[7];
    const float* bias  = (const float*)d_in[8];
    float* out = (float*)d_out;

    char* ws = (char*)d_ws;
    int*                headptr  = (int*)(ws + 0);
    unsigned*           barA     = (unsigned*)(ws + 81920);
    unsigned*           barB     = (unsigned*)(ws + 82048);
    unsigned*           nodeNext = (unsigned*)(ws + 90112);
    unsigned long long* nodeBm   = (unsigned long long*)(ws + 983040);

    hipLaunchKernelGGL(k_fused, dim3(kBlocks), dim3(kT), 0, stream,
                       all_h, rem, eh, er, et, rb, rw, bias, out,
                       headptr, nodeNext, nodeBm, barA, barB);
}

// Round 8
// 98.143 us; speedup vs baseline: 1.8366x; 1.2520x over previous
//
#include <hip/hip_runtime.h>

// Predictor_8924942041234 — 2-hop rule grounding over a KG, ONE dispatch.
// x0 one-hot -> hop1 frontier (~640 matching edges); rules collapse to
// W[r1][r2] (24x24); hop2 = stream all E edges + O(1) per-head-entity chain
// probe. Single plain launch, FENCE-FREE software grid barrier.
//
// COHERENCE MODEL (rounds 5-7 lessons):
//  * agent-scope FENCES (buffer_wbl2/buffer_inv = 4MiB L2 tag walks) are the
//    enemy: per-spin = 115us, once-per-block = +50us. Use NONE.
//  * agent-scope atomic RMWs + relaxed atomic loads/stores execute at the
//    IF/MALL coherence point (round-6 spins observed remote fetch_adds with
//    no inv in the loop -> relaxed atomic loads are coherent).
//  * THE ROUND-7 BUG: plain stores (dirty in local XCD L2) mixed with
//    remote atomicAdd (at MALL) on the same lines of `out` -> both copies
//    diverge, kernel-end flush clobbers. FIX: out-init uses agent-scope
//    relaxed atomic u64 stores (sc1 write-through, never dirty in L2), so
//    ALL writers of `out` meet at the coherence point.
//
// Barrier safety: 512 blocks = 2/CU x 256 CUs, co-resident via
// __launch_bounds__(256,2) -> no deadlock; bounded spin as a guard.
// Poisoned-ws handshake: block 0 stores barA=0, s_waitcnt, barB=MAGIC;
// arrivers spin (relaxed) on MAGIC before adding to barA.
// headptr needs no init: entries store e+1 (>=1); poison/zero reads <= 0.
// Phase-C edge data (h,r2,t2,valid) is preloaded into registers in phase B.

namespace {
constexpr int kNEnt    = 20000;
constexpr int kNRel    = 24;
constexpr int kNEdge   = 200000;
constexpr int kBatch   = 64;
constexpr int kNRules  = 32;
constexpr int kWSz     = kNRel * kNRel;          // 576
constexpr int kBlocks  = 512;                    // 2 blocks/CU -> co-resident
constexpr int kT       = 256;
constexpr int kGT      = kBlocks * kT;           // 131072
constexpr int kRow8    = kNEnt / 2;              // 2500 u64 per [b,:] row
constexpr int kScore8  = kBatch * kRow8;         // 160000 u64 (score)
constexpr int kOut8    = 2 * kScore8;            // 320000 u64 (score+mask)
constexpr unsigned kMagic     = 0x5EEDF00Du;
constexpr unsigned kSpinLimit = 1u << 20;        // hang guard, never hit
constexpr unsigned long long kOnePair = 0x3F8000003F800000ull; // {1.f,1.f}
// ws layout (bytes):
//   0       headptr[20000] int   (e+1 of chain head; <=0 empty; NO init)
//   81920   barA (arrival count)   — own cache line
//   82048   barB (init-magic flag) — own cache line
//   90112   nodeNext[200000] u32 (prev headptr value (or 0) | r1<<24)
//   983040  nodeBm[200000] u64   (which b's matched hop1 edge e)
}

__global__ void __launch_bounds__(kT, 2) k_fused(
        const int* __restrict__ all_h,
        const int* __restrict__ rem,
        const int* __restrict__ eh,
        const int* __restrict__ er,
        const int* __restrict__ et,
        const int* __restrict__ rb,
        const float* __restrict__ rw,
        const float* __restrict__ bias,
        float* __restrict__ out,
        int* __restrict__ headptr,
        unsigned* __restrict__ nodeNext,
        unsigned long long* __restrict__ nodeBm,
        unsigned* __restrict__ barA,
        unsigned* __restrict__ barB) {
    __shared__ int   sh[kBatch];
    __shared__ int   srem[kBatch];
    __shared__ float sW[kWSz];
    const int t = threadIdx.x;

    // barrier-counter init handshake, ordered by explicit waitcnt
    if (blockIdx.x == 0 && t == 0) {
        __hip_atomic_store(barA, 0u, __ATOMIC_RELAXED, __HIP_MEMORY_SCOPE_AGENT);
        __builtin_amdgcn_s_waitcnt(0);     // barA=0 acked before MAGIC visible
        __hip_atomic_store(barB, kMagic, __ATOMIC_RELAXED, __HIP_MEMORY_SCOPE_AGENT);
    }

    if (t < kBatch) sh[t] = all_h[t];
    else if (t < 2 * kBatch) srem[t - kBatch] = rem[t - kBatch];
    for (int i = t; i < kWSz; i += kT) sW[i] = 0.f;
    __syncthreads();
    if (t < kNRules)
        atomicAdd(&sW[rb[2 * t] * kNRel + rb[2 * t + 1]], rw[t]);
    // (sW only read in phase C, after the barrier's closing __syncthreads)

    const int gid = blockIdx.x * kT + t;

    // ---- Phase A: out init — score[b,:]=bias, mask[b,:]=1 ----
    // Agent-scope atomic u64 stores: write-through to the coherence point so
    // phase-C atomicAdds (also at the coherence point) RMW the real values
    // and no dirty L2 copy of `out` exists anywhere to clobber them later.
    {
        unsigned long long*       out8  = (unsigned long long*)out;
        const unsigned long long* bias8 = (const unsigned long long*)bias;
        for (int i = gid; i < kOut8; i += kGT) {
            unsigned long long v =
                (i < kScore8) ? bias8[i % kRow8] : kOnePair;
            __hip_atomic_store(&out8[i], v, __ATOMIC_RELAXED,
                               __HIP_MEMORY_SCOPE_AGENT);
        }
    }

    // ---- Phase B: hop1 frontier chains (coherent writes) + reg preload ----
    int  ph[2], pr[2], pt[2];
    bool pok[2];
#pragma unroll
    for (int j = 0; j < 2; j++) {
        int e = gid + j * kGT;
        pok[j] = false;
        ph[j] = 0; pr[j] = 0; pt[j] = 0;
        if (e < kNEdge) {
            int h  = eh[e];
            int r  = er[e];
            int tl = et[e];
            bool removed = false;
            for (int i = 0; i < kBatch; i++) removed |= (srem[i] == e);
            if (!removed) {
                pok[j] = true; ph[j] = h; pr[j] = r; pt[j] = tl;
                unsigned long long bm = 0ull;
                for (int b = 0; b < kBatch; b++)
                    bm |= (unsigned long long)(sh[b] == h) << b;
                if (bm) {
                    int old = __hip_atomic_exchange(&headptr[tl], e + 1,
                                                    __ATOMIC_RELAXED,
                                                    __HIP_MEMORY_SCOPE_AGENT);
                    unsigned nx = ((old <= 0) ? 0u : (unsigned)old)
                                | ((unsigned)r << 24);
                    __hip_atomic_store(&nodeNext[e], nx, __ATOMIC_RELAXED,
                                       __HIP_MEMORY_SCOPE_AGENT);
                    __hip_atomic_store(&nodeBm[e], bm, __ATOMIC_RELAXED,
                                       __HIP_MEMORY_SCOPE_AGENT);
                }
            }
        }
    }

    // ---- fence-free grid barrier: syncthreads' vmcnt(0) is the release ----
    __syncthreads();                 // all sc1 stores acked at coherence point
    if (t == 0) {
        unsigned tries = 0;
        while (__hip_atomic_load(barB, __ATOMIC_RELAXED,
                                 __HIP_MEMORY_SCOPE_AGENT) != kMagic &&
               ++tries < kSpinLimit)
            __builtin_amdgcn_s_sleep(1);
        __hip_atomic_fetch_add(barA, 1u, __ATOMIC_RELAXED,
                               __HIP_MEMORY_SCOPE_AGENT);
        tries = 0;
        while (__hip_atomic_load(barA, __ATOMIC_RELAXED,
                                 __HIP_MEMORY_SCOPE_AGENT) < (unsigned)kBlocks &&
               ++tries < kSpinLimit)
            __builtin_amdgcn_s_sleep(1);
    }
    __syncthreads();

    // ---- Phase C: hop2 — probe chain per preloaded edge, scatter W ----
#pragma unroll
    for (int j = 0; j < 2; j++) {
        if (!pok[j]) continue;
        int p = __hip_atomic_load(&headptr[ph[j]], __ATOMIC_RELAXED,
                                  __HIP_MEMORY_SCOPE_AGENT);
        if (p <= 0) continue;                  // ~97% of edges exit here
        int r2 = pr[j];
        int t2 = pt[j];
        while (p > 0) {
            int e1 = p - 1;
            unsigned nx = __hip_atomic_load(&nodeNext[e1], __ATOMIC_RELAXED,
                                            __HIP_MEMORY_SCOPE_AGENT);
            unsigned long long bm = __hip_atomic_load(&nodeBm[e1],
                                                      __ATOMIC_RELAXED,
                                                      __HIP_MEMORY_SCOPE_AGENT);
            float w = sW[((nx >> 24) & 31u) * kNRel + r2];
            while (bm) {
                int b = __ffsll(bm) - 1;
                bm &= bm - 1;
                atomicAdd(&out[b * kNEnt + t2], w);   // device-scope, at MALL
            }
            p = (int)(nx & 0xFFFFFFu);
        }
    }
}

extern "C" void kernel_launch(void* const* d_in, const int* in_sizes, int n_in,
                              void* d_out, int out_size, void* d_ws, size_t ws_size,
                              hipStream_t stream) {
    const int*   all_h = (const int*)d_in[0];
    // d_in[1] = all_r (unused by the reference)
    const int*   rem   = (const int*)d_in[2];
    const int*   eh    = (const int*)d_in[3];
    const int*   er    = (const int*)d_in[4];
    const int*   et    = (const int*)d_in[5];
    const int*   rb    = (const int*)d_in[6];
    const float* rw    = (const float*)d_in[7];
    const float* bias  = (const float*)d_in[8];
    float* out = (float*)d_out;

    char* ws = (char*)d_ws;
    int*                headptr  = (int*)(ws + 0);
    unsigned*           barA     = (unsigned*)(ws + 81920);
    unsigned*           barB     = (unsigned*)(ws + 82048);
    unsigned*           nodeNext = (unsigned*)(ws + 90112);
    unsigned long long* nodeBm   = (unsigned long long*)(ws + 983040);

    hipLaunchKernelGGL(k_fused, dim3(kBlocks), dim3(kT), 0, stream,
                       all_h, rem, eh, er, et, rb, rw, bias, out,
                       headptr, nodeNext, nodeBm, barA, barB);
}